// Round 5
// baseline (52.003 us; speedup 1.0000x reference)
//
#include <hip/hip_runtime.h>
#include <math.h>
#include <stdint.h>

#define N_AGENTS 2048
#define R_CAND   128
#define NUM_MODS 6
#define T_STEPS  30
#define B_BATCH  16

// out layout: [0]=cls_loss, [1]=reg_loss, [2..5761]=traj_eval(16,6,30,2), [5762]=num_cls, [5763]=num_reg

__global__ __launch_bounds__(128) void agent_kernel(
    const float* __restrict__ roi,      // [N*R,5]  (logit, dx, dy, d2, d3)
    const float* __restrict__ anchor,   // [N*R,4]
    const float* __restrict__ ctrs,     // [N,2]
    const float* __restrict__ feats,    // [N,20,3]
    const float* __restrict__ gt,       // [N,T,2]
    const int* __restrict__ has,        // [N,T] bool -> int32
    const int* __restrict__ natgs,      // [B]
    float* __restrict__ out,
    float* __restrict__ part)           // [N,4] cls,reg,ncls,nreg
{
    const int a   = blockIdx.x;
    const int tid = threadIdx.x;

    __shared__ float    s_logic[R_CAND];                  // orig order
    __shared__ float    s_gx[R_CAND], s_gy[R_CAND], s_g2[R_CAND], s_g3[R_CAND];
    __shared__ float    s_sx[R_CAND], s_sy[R_CAND];       // sorted by logit desc
    __shared__ int      s_sidx[R_CAND];                   // sorted pos -> orig idx
    __shared__ uint64_t s_row[R_CAND][2];                 // suppression rows (bits j>i)
    __shared__ float    s_d[R_CAND];  __shared__ int s_i[R_CAND];
    __shared__ float    s_gtrow[T_STEPS * 2];
    __shared__ int      s_has[T_STEPS];
    __shared__ int      s_win[NUM_MODS];
    __shared__ float    s_slog[NUM_MODS];
    __shared__ float    s_coef[NUM_MODS][6];
    __shared__ float    s_traj[NUM_MODS][T_STEPS][2];
    __shared__ float    s_red[66];
    __shared__ int      s_mi, s_mask;

    // ---- 1. load candidates + per-agent rows
    {
        const float* rp  = roi    + (size_t)(a * R_CAND + tid) * 5;
        const float* apr = anchor + (size_t)(a * R_CAND + tid) * 4;
        s_logic[tid] = rp[0];
        s_gx[tid] = apr[0] + rp[1];
        s_gy[tid] = apr[1] + rp[2];
        s_g2[tid] = apr[2] + rp[3];
        s_g3[tid] = apr[3] + rp[4];
    }
    if (tid < T_STEPS * 2) s_gtrow[tid] = gt[(size_t)a * T_STEPS * 2 + tid];
    if (tid >= 64 && tid < 64 + T_STEPS) s_has[tid - 64] = has[(size_t)a * T_STEPS + (tid - 64)];
    __syncthreads();

    // ---- 2. rank = stable argsort(-logic) position (keys are raw f32 inputs: exact)
    {
        const float lr = s_logic[tid];
        int rank = 0;
        for (int j = 0; j < R_CAND; ++j) {
            const float lj = s_logic[j];
            rank += (lj > lr) || (lj == lr && j < tid);
        }
        s_sidx[rank] = tid;
        s_sx[rank]   = s_gx[tid];
        s_sy[rank]   = s_gy[tid];
    }
    __syncthreads();

    // ---- 3a. suppression rows. Boxes are all 0.5x0.5 =>
    //      iou>0.5  <=>  inter > 1/6  <=>  wx*wy > 1/6, wx=0.5-|dx|, wy=0.5-|dy|
    {
        const int i = tid;
        const float xi = s_sx[i], yi = s_sy[i];
        uint64_t r0 = 0, r1 = 0;
        for (int j = i + 1; j < R_CAND; ++j) {
            const float wx = 0.5f - fabsf(xi - s_sx[j]);
            const float wy = 0.5f - fabsf(yi - s_sy[j]);
            const unsigned sup = (wx > 0.0f) & (wy > 0.0f) & (wx * wy > (1.0f / 6.0f));
            if (j < 64) r0 |= (uint64_t)sup << j;
            else        r1 |= (uint64_t)sup << (j - 64);
        }
        s_row[i][0] = r0;
        s_row[i][1] = r1;
    }
    __syncthreads();

    // ---- 3b. greedy scan (redundant in all threads; LDS broadcast reads, no barriers)
    uint64_t keep0 = ~0ull, keep1 = ~0ull;
    for (int i = 0; i < 64; ++i) {
        if ((keep0 >> i) & 1ull) {
            keep0 &= ~s_row[i][0];
            keep1 &= ~s_row[i][1];
        }
    }
    for (int i = 0; i < 64; ++i) {
        if ((keep1 >> i) & 1ull) {
            keep1 &= ~s_row[64 + i][1];   // rows i>=64 have word0 == 0
        }
    }
    const int kcnt  = __popcll(keep0) + __popcll(keep1);
    const int kfall = (kcnt < NUM_MODS);   // keep everything if fewer than 6 survive

    // ---- 4. dist to gt endpoint, stable top-6 by (dist, orig idx)
    {
        const float gtx = s_gtrow[(T_STEPS - 1) * 2 + 0];
        const float gty = s_gtrow[(T_STEPS - 1) * 2 + 1];
        const int keptbit = (tid < 64) ? (int)((keep0 >> tid) & 1ull)
                                       : (int)((keep1 >> (tid - 64)) & 1ull);
        const int kept = kfall ? 1 : keptbit;
        s_d[tid] = kept ? (fabsf(s_sx[tid] - gtx) + fabsf(s_sy[tid] - gty)) : INFINITY;
        s_i[tid] = s_sidx[tid];
    }
    __syncthreads();

    if (tid < 64) {
        float d_lo = s_d[tid],      d_hi = s_d[tid + 64];
        int   i_lo = s_i[tid],      i_hi = s_i[tid + 64];
        for (int m = 0; m < NUM_MODS; ++m) {
            float bd; int bi;
            if (d_lo < d_hi || (d_lo == d_hi && i_lo < i_hi)) { bd = d_lo; bi = i_lo; }
            else                                               { bd = d_hi; bi = i_hi; }
            for (int off = 32; off >= 1; off >>= 1) {
                const float od = __shfl_down(bd, (unsigned)off, 64);
                const int   oi = __shfl_down(bi, (unsigned)off, 64);
                if (od < bd || (od == bd && oi < bi)) { bd = od; bi = oi; }
            }
            bi = __shfl(bi, 0, 64);
            if (tid == 0) s_win[m] = bi;
            if (i_lo == bi) d_lo = INFINITY;
            if (i_hi == bi) d_hi = INFINITY;
        }
    }
    __syncthreads();

    // ---- 5. coefficients (tid<6) + trajectories
    if (tid < NUM_MODS) {
        const int m = tid, win = s_win[m];
        const float ap0 = ctrs[(size_t)a * 2 + 0];
        const float ap1 = ctrs[(size_t)a * 2 + 1];
        const float ap2 = feats[((size_t)a * 20 + 19) * 3 + 0];
        const float ap3 = feats[((size_t)a * 20 + 19) * 3 + 1];
        const float sel0 = s_gx[win], sel1 = s_gy[win];
        const float sel2 = s_g2[win], sel3 = s_g3[win];
        s_slog[m] = s_logic[win];
        const float a1c = (2.0f * sel0 * ap2 + 2.0f * ap0 * ap2) / (2.0f + ap2 - sel2);
        const float a0c = sel0 - ap0 - a1c;
        const float b1c = (2.0f * sel1 * ap3 + 2.0f * ap1 * ap3) / (2.0f + ap3 - sel3);
        const float b0c = sel1 - ap1 - b1c;
        s_coef[m][0] = a0c; s_coef[m][1] = a1c; s_coef[m][2] = ap0;
        s_coef[m][3] = b0c; s_coef[m][4] = b1c; s_coef[m][5] = ap1;
    }
    __syncthreads();
    for (int p = tid; p < NUM_MODS * T_STEPS; p += 128) {   // 180 > 128: strided
        const int m = p / T_STEPS, t = p % T_STEPS;
        const float s1 = (float)t / (float)(T_STEPS - 1);
        const float s2 = s1 * s1;
        s_traj[m][t][0] = s_coef[m][0] * s2 + s_coef[m][1] * s1 + s_coef[m][2];
        s_traj[m][t][1] = s_coef[m][3] * s2 + s_coef[m][4] * s1 + s_coef[m][5];
    }
    __syncthreads();

    // ---- 6a. last-timestep + best-mode (thread 0, tiny)
    if (tid == 0) {
        float best = -1e30f; int lt = 0;
        for (int t = 0; t < T_STEPS; ++t) {
            const float h = s_has[t] ? 1.0f : 0.0f;
            const float v = h + (0.1f * (float)t) / (float)T_STEPS;
            if (v > best) { best = v; lt = t; }
        }
        const int mask = (best > 1.0f);
        const float egx = s_gtrow[lt * 2 + 0];
        const float egy = s_gtrow[lt * 2 + 1];
        float bd = 1e30f; int mi = 0;
        for (int m = 0; m < NUM_MODS; ++m) {
            const float dx = s_traj[m][lt][0] - egx;
            const float dy = s_traj[m][lt][1] - egy;
            const float d = sqrtf(dx * dx + dy * dy);
            if (d < bd) { bd = d; mi = m; }
        }
        s_mi = mi; s_mask = mask;
    }
    __syncthreads();

    // ---- 6b. loss terms in parallel
    if (tid < NUM_MODS) {
        const float l = s_slog[tid];
        const float g = (tid == s_mi) ? 1.0f : 0.0f;
        s_red[tid] = fmaxf(l, 0.0f) - l * g + log1pf(expf(-fabsf(l)));
    } else if (tid < NUM_MODS + 2 * T_STEPS) {
        const int p = tid - NUM_MODS;
        const int t = p >> 1, c = p & 1;
        float v = 0.0f;
        if (s_mask && s_has[t]) {
            const float diff = s_traj[s_mi][t][c] - s_gtrow[t * 2 + c];
            const float ad = fabsf(diff);
            v = (ad < 1.0f) ? 0.5f * diff * diff : (ad - 0.5f);
        }
        s_red[NUM_MODS + p] = v;
    }
    __syncthreads();

    if (tid == 0) {
        float cls = 0.0f;
        for (int m = 0; m < NUM_MODS; ++m) cls += s_red[m];
        if (!s_mask) cls = 0.0f;
        float reg = 0.0f;
        for (int p = 0; p < 2 * T_STEPS; ++p) reg += s_red[NUM_MODS + p];
        int nh = 0;
        for (int t = 0; t < T_STEPS; ++t) nh += (s_has[t] != 0);
        part[(size_t)a * 4 + 0] = cls;
        part[(size_t)a * 4 + 1] = reg;
        part[(size_t)a * 4 + 2] = s_mask ? 1.0f : 0.0f;
        part[(size_t)a * 4 + 3] = s_mask ? (float)nh : 0.0f;
    }

    // ---- 7. traj_eval gather (temp is NOT cumsum: [0, natgs[0], ..., natgs[14]])
    const float* tp = &s_traj[0][0][0];
    for (int b = 0; b < B_BATCH; ++b) {
        const int target = (b == 0) ? 0 : natgs[b - 1];
        if (target == a) {
            for (int p = tid; p < NUM_MODS * T_STEPS * 2; p += 128)
                out[2 + (size_t)b * NUM_MODS * T_STEPS * 2 + p] = tp[p];
        }
    }
}

__global__ __launch_bounds__(256) void reduce_kernel(
    const float* __restrict__ part, float* __restrict__ out)
{
    __shared__ double s0[256], s1[256], s2[256], s3[256];
    const int tid = threadIdx.x;
    double c = 0, r = 0, n = 0, w = 0;
    for (int a = tid; a < N_AGENTS; a += 256) {
        c += (double)part[(size_t)a * 4 + 0];
        r += (double)part[(size_t)a * 4 + 1];
        n += (double)part[(size_t)a * 4 + 2];
        w += (double)part[(size_t)a * 4 + 3];
    }
    s0[tid] = c; s1[tid] = r; s2[tid] = n; s3[tid] = w;
    __syncthreads();
    for (int off = 128; off >= 1; off >>= 1) {
        if (tid < off) {
            s0[tid] += s0[tid + off]; s1[tid] += s1[tid + off];
            s2[tid] += s2[tid + off]; s3[tid] += s3[tid + off];
        }
        __syncthreads();
    }
    if (tid == 0) {
        out[0]    = (float)s0[0];
        out[1]    = (float)s1[0];
        out[5762] = (float)s2[0];
        out[5763] = (float)s3[0];
    }
}

extern "C" void kernel_launch(void* const* d_in, const int* in_sizes, int n_in,
                              void* d_out, int out_size, void* d_ws, size_t ws_size,
                              hipStream_t stream) {
    const float*   roi    = (const float*)d_in[0];
    const float*   anchor = (const float*)d_in[1];
    const float*   ctrs   = (const float*)d_in[2];
    const float*   feats  = (const float*)d_in[3];
    const float*   gt     = (const float*)d_in[4];
    const int*     has    = (const int*)d_in[5];
    const int*     natgs  = (const int*)d_in[6];
    float* out  = (float*)d_out;
    float* part = (float*)d_ws;   // 2048*4 floats = 32 KB

    agent_kernel<<<N_AGENTS, 128, 0, stream>>>(roi, anchor, ctrs, feats, gt, has, natgs, out, part);
    reduce_kernel<<<1, 256, 0, stream>>>(part, out);
}

// Round 6
// 36.659 us; speedup vs baseline: 1.4186x; 1.4186x over previous
//
#include <hip/hip_runtime.h>
#include <math.h>
#include <stdint.h>

#define N_AGENTS 2048
#define R_CAND   128
#define NUM_MODS 6
#define T_STEPS  30
#define B_BATCH  16

// out layout: [0]=cls_loss, [1]=reg_loss, [2..5761]=traj_eval(16,6,30,2), [5762]=num_cls, [5763]=num_reg

__global__ __launch_bounds__(128) void agent_kernel(
    const float* __restrict__ roi,      // [N*R,5]
    const float* __restrict__ anchor,   // [N*R,4]
    const float* __restrict__ ctrs,     // [N,2]
    const float* __restrict__ feats,    // [N,20,3]
    const float* __restrict__ gt,       // [N,T,2]
    const int* __restrict__ has,        // [N,T] bool -> int32
    const int* __restrict__ natgs,      // [B]
    float* __restrict__ out,
    float* __restrict__ part)           // [N,4]
{
    const int a   = blockIdx.x;
    const int tid = threadIdx.x;

    __shared__ float    s_stage[R_CAND * 5];
    __shared__ float4   s_goal[R_CAND];            // orig order (gx,gy,g2,g3)
    __shared__ float    s_logic[R_CAND];           // orig order
    __shared__ float2   s_pos[R_CAND];             // sorted by logit desc
    __shared__ int      s_sidx[R_CAND];            // sorted pos -> orig idx
    __shared__ float    s_d[R_CAND];               // dist (sorted order)
    __shared__ uint64_t s_colhi[64][2];            // columns for j=64..127
    __shared__ float    s_gtrow[T_STEPS * 2];
    __shared__ int      s_has[T_STEPS];
    __shared__ float    s_coef[NUM_MODS][6];
    __shared__ float    s_traj[NUM_MODS][T_STEPS][2];

    // ---- A1: coalesced loads / staging
    {
        const float* rbase = roi + (size_t)a * R_CAND * 5;
        #pragma unroll
        for (int k = 0; k < 5; ++k) s_stage[tid + k * 128] = rbase[tid + k * 128];
    }
    const float4 anc = *reinterpret_cast<const float4*>(anchor + (size_t)(a * R_CAND + tid) * 4);
    if (tid < T_STEPS * 2) s_gtrow[tid] = gt[(size_t)a * T_STEPS * 2 + tid];
    if (tid >= 64 && tid < 64 + T_STEPS) s_has[tid - 64] = has[(size_t)a * T_STEPS + (tid - 64)];
    __syncthreads();

    // ---- A2: logits + goals (stride-5 LDS read: 5 coprime 32 -> conflict-free)
    float lg, gx, gy;
    {
        const float* rp = &s_stage[tid * 5];
        lg = rp[0];
        gx = anc.x + rp[1];
        gy = anc.y + rp[2];
        s_logic[tid] = lg;
        s_goal[tid]  = make_float4(gx, gy, anc.z + rp[3], anc.w + rp[4]);
    }
    __syncthreads();

    // ---- B: rank = stable argsort(-logic) position (float4 LDS loads)
    {
        int rank = 0;
        for (int j = 0; j < R_CAND; j += 4) {
            const float4 v = *reinterpret_cast<const float4*>(&s_logic[j]);
            rank += (v.x > lg) || (v.x == lg && (j + 0) < tid);
            rank += (v.y > lg) || (v.y == lg && (j + 1) < tid);
            rank += (v.z > lg) || (v.z == lg && (j + 2) < tid);
            rank += (v.w > lg) || (v.w == lg && (j + 3) < tid);
        }
        s_pos[rank]  = make_float2(gx, gy);
        s_sidx[rank] = tid;
    }
    __syncthreads();

    // ---- C: suppression COLUMNS (lane j: bits i<j with iou>0.5) + dist
    //      boxes 0.5x0.5: iou>0.5 <=> wx>0 && wx*wy>1/6, wx=0.5-|dx|
    uint64_t c0 = 0;
    {
        const int j = tid;
        const float2 pj = s_pos[j];
        uint64_t c1 = 0;
        const int e0 = (j < 64) ? j : 64;
        for (int i = 0; i < e0; ++i) {
            const float2 pi = s_pos[i];
            const float wx = 0.5f - fabsf(pj.x - pi.x);
            const float wy = 0.5f - fabsf(pj.y - pi.y);
            if (wx > 0.0f && wx * wy > (1.0f / 6.0f)) c0 |= 1ull << i;
        }
        for (int i = 64; i < j; ++i) {
            const float2 pi = s_pos[i];
            const float wx = 0.5f - fabsf(pj.x - pi.x);
            const float wy = 0.5f - fabsf(pj.y - pi.y);
            if (wx > 0.0f && wx * wy > (1.0f / 6.0f)) c1 |= 1ull << (i - 64);
        }
        if (tid >= 64) { s_colhi[tid - 64][0] = c0; s_colhi[tid - 64][1] = c1; }
        s_d[tid] = fabsf(pj.x - s_gtrow[(T_STEPS - 1) * 2]) + fabsf(pj.y - s_gtrow[(T_STEPS - 1) * 2 + 1]);
    }
    __syncthreads();

    // ---- D (wave 0): ballot-fixpoint NMS -> top-6 -> coefficients
    float my_slog = 0.0f; int my_win = 0;   // valid on lanes 0..5
    if (tid < 64) {
        const uint64_t cl0 = c0;                            // column of j=tid (word1==0)
        const uint64_t ch0 = s_colhi[tid][0], ch1 = s_colhi[tid][1];
        uint64_t k0 = ~0ull, k1 = ~0ull;
        for (int it = 0; it < 200; ++it) {                  // fixpoint == greedy NMS
            const int slo = ((cl0 & k0) != 0);
            const int shi = (((ch0 & k0) | (ch1 & k1)) != 0);
            const uint64_t n0 = ~__ballot(slo);
            const uint64_t n1 = ~__ballot(shi);
            if (n0 == k0 && n1 == k1) break;
            k0 = n0; k1 = n1;
        }
        const int kfall = (__popcll(k0) + __popcll(k1)) < NUM_MODS;
        float d_lo = (kfall | (int)((k0 >> tid) & 1)) ? s_d[tid]      : INFINITY;
        float d_hi = (kfall | (int)((k1 >> tid) & 1)) ? s_d[tid + 64] : INFINITY;
        int   i_lo = s_sidx[tid], i_hi = s_sidx[tid + 64];
        for (int m = 0; m < NUM_MODS; ++m) {
            float bd; int bi;
            if (d_lo < d_hi || (d_lo == d_hi && i_lo < i_hi)) { bd = d_lo; bi = i_lo; }
            else                                               { bd = d_hi; bi = i_hi; }
            for (int off = 32; off >= 1; off >>= 1) {
                const float od = __shfl_down(bd, (unsigned)off, 64);
                const int   oi = __shfl_down(bi, (unsigned)off, 64);
                if (od < bd || (od == bd && oi < bi)) { bd = od; bi = oi; }
            }
            bi = __shfl(bi, 0, 64);
            if (tid == m) my_win = bi;
            if (i_lo == bi) d_lo = INFINITY;
            if (i_hi == bi) d_hi = INFINITY;
        }
        if (tid < NUM_MODS) {
            const float ap0 = ctrs[(size_t)a * 2 + 0];
            const float ap1 = ctrs[(size_t)a * 2 + 1];
            const float ap2 = feats[((size_t)a * 20 + 19) * 3 + 0];
            const float ap3 = feats[((size_t)a * 20 + 19) * 3 + 1];
            const float4 g = s_goal[my_win];
            my_slog = s_logic[my_win];
            const float a1c = (2.f * g.x * ap2 + 2.f * ap0 * ap2) / (2.f + ap2 - g.z);
            const float a0c = g.x - ap0 - a1c;
            const float b1c = (2.f * g.y * ap3 + 2.f * ap1 * ap3) / (2.f + ap3 - g.w);
            const float b0c = g.y - ap1 - b1c;
            s_coef[tid][0] = a0c; s_coef[tid][1] = a1c; s_coef[tid][2] = ap0;
            s_coef[tid][3] = b0c; s_coef[tid][4] = b1c; s_coef[tid][5] = ap1;
        }
    }
    __syncthreads();

    // ---- E: trajectories (180 elems, strided)
    for (int p = tid; p < NUM_MODS * T_STEPS; p += 128) {
        const int m = p / T_STEPS, t = p % T_STEPS;
        const float s1 = (float)t / (float)(T_STEPS - 1);
        const float s2 = s1 * s1;
        s_traj[m][t][0] = s_coef[m][0] * s2 + s_coef[m][1] * s1 + s_coef[m][2];
        s_traj[m][t][1] = s_coef[m][3] * s2 + s_coef[m][4] * s1 + s_coef[m][5];
    }
    __syncthreads();

    // ---- F (wave 0): losses  ||  G (wave 1): traj_eval gather
    if (tid < 64) {
        // lt = argmax over t (values distinct; first-max tie-break kept anyway)
        float bv = -1e30f; int bt = tid;
        if (tid < T_STEPS) bv = (s_has[tid] ? 1.0f : 0.0f) + (0.1f * (float)tid) / (float)T_STEPS;
        for (int off = 16; off >= 1; off >>= 1) {
            const float ov = __shfl_down(bv, (unsigned)off, 32);
            const int   ot = __shfl_down(bt, (unsigned)off, 32);
            if (ov > bv || (ov == bv && ot < bt)) { bv = ov; bt = ot; }
        }
        const int   lt   = __shfl(bt, 0, 64);
        const float bmax = __shfl(bv, 0, 64);
        const int   mask = bmax > 1.0f;
        const float egx = s_gtrow[lt * 2 + 0], egy = s_gtrow[lt * 2 + 1];
        // mi = argmin over 6 modes
        float md = 1e30f; int mm = tid;
        if (tid < NUM_MODS) {
            const float dx = s_traj[tid][lt][0] - egx;
            const float dy = s_traj[tid][lt][1] - egy;
            md = sqrtf(dx * dx + dy * dy);
        }
        for (int off = 4; off >= 1; off >>= 1) {
            const float ov = __shfl_down(md, (unsigned)off, 8);
            const int   om = __shfl_down(mm, (unsigned)off, 8);
            if (ov < md || (ov == md && om < mm)) { md = ov; mm = om; }
        }
        const int mi = __shfl(mm, 0, 64);
        // cls (lanes 0..5) -> width-8 sum
        float cv = 0.0f;
        if (tid < NUM_MODS) {
            const float l = my_slog;
            const float g = (tid == mi) ? 1.0f : 0.0f;
            cv = fmaxf(l, 0.0f) - l * g + log1pf(expf(-fabsf(l)));
        }
        cv += __shfl_xor(cv, 4, 8); cv += __shfl_xor(cv, 2, 8); cv += __shfl_xor(cv, 1, 8);
        // reg terms (lanes 0..59) -> width-64 sum
        float rv = 0.0f;
        if (tid < 2 * T_STEPS) {
            const int t = tid >> 1, c = tid & 1;
            if (mask && s_has[t]) {
                const float diff = s_traj[mi][t][c] - s_gtrow[t * 2 + c];
                const float ad = fabsf(diff);
                rv = (ad < 1.0f) ? 0.5f * diff * diff : (ad - 0.5f);
            }
        }
        for (int off = 32; off >= 1; off >>= 1) rv += __shfl_xor(rv, (unsigned)off, 64);
        const int hv = (tid < T_STEPS) ? s_has[tid] : 0;
        const int nh = __popcll(__ballot(hv != 0));
        if (tid == 0) {
            part[(size_t)a * 4 + 0] = mask ? cv : 0.0f;
            part[(size_t)a * 4 + 1] = rv;
            part[(size_t)a * 4 + 2] = mask ? 1.0f : 0.0f;
            part[(size_t)a * 4 + 3] = mask ? (float)nh : 0.0f;
        }
    } else {
        // gather (temp is NOT cumsum: [0, natgs[0], ..., natgs[14]])
        const float* tp = &s_traj[0][0][0];
        const int p = tid - 64;
        for (int b = 0; b < B_BATCH; ++b) {
            const int target = (b == 0) ? 0 : natgs[b - 1];
            if (target == a) {
                for (int q = p; q < NUM_MODS * T_STEPS * 2; q += 64)
                    out[2 + (size_t)b * NUM_MODS * T_STEPS * 2 + q] = tp[q];
            }
        }
    }
}

__global__ __launch_bounds__(256) void reduce_kernel(
    const float* __restrict__ part, float* __restrict__ out)
{
    __shared__ double s0[256], s1[256], s2[256], s3[256];
    const int tid = threadIdx.x;
    double c = 0, r = 0, n = 0, w = 0;
    for (int a = tid; a < N_AGENTS; a += 256) {
        c += (double)part[(size_t)a * 4 + 0];
        r += (double)part[(size_t)a * 4 + 1];
        n += (double)part[(size_t)a * 4 + 2];
        w += (double)part[(size_t)a * 4 + 3];
    }
    s0[tid] = c; s1[tid] = r; s2[tid] = n; s3[tid] = w;
    __syncthreads();
    for (int off = 128; off >= 1; off >>= 1) {
        if (tid < off) {
            s0[tid] += s0[tid + off]; s1[tid] += s1[tid + off];
            s2[tid] += s2[tid + off]; s3[tid] += s3[tid + off];
        }
        __syncthreads();
    }
    if (tid == 0) {
        out[0]    = (float)s0[0];
        out[1]    = (float)s1[0];
        out[5762] = (float)s2[0];
        out[5763] = (float)s3[0];
    }
}

extern "C" void kernel_launch(void* const* d_in, const int* in_sizes, int n_in,
                              void* d_out, int out_size, void* d_ws, size_t ws_size,
                              hipStream_t stream) {
    const float*   roi    = (const float*)d_in[0];
    const float*   anchor = (const float*)d_in[1];
    const float*   ctrs   = (const float*)d_in[2];
    const float*   feats  = (const float*)d_in[3];
    const float*   gt     = (const float*)d_in[4];
    const int*     has    = (const int*)d_in[5];
    const int*     natgs  = (const int*)d_in[6];
    float* out  = (float*)d_out;
    float* part = (float*)d_ws;   // 2048*4 floats = 32 KB

    agent_kernel<<<N_AGENTS, 128, 0, stream>>>(roi, anchor, ctrs, feats, gt, has, natgs, out, part);
    reduce_kernel<<<1, 256, 0, stream>>>(part, out);
}

// Round 7
// 30.022 us; speedup vs baseline: 1.7322x; 1.2211x over previous
//
#include <hip/hip_runtime.h>
#include <math.h>
#include <stdint.h>

#define N_AGENTS 2048
#define R_CAND   128
#define NUM_MODS 6
#define T_STEPS  30
#define B_BATCH  16

// out layout: [0]=cls_loss, [1]=reg_loss, [2..5761]=traj_eval(16,6,30,2), [5762]=num_cls, [5763]=num_reg

__global__ __launch_bounds__(128) void agent_kernel(
    const float* __restrict__ roi,      // [N*R,5]
    const float* __restrict__ anchor,   // [N*R,4]
    const float* __restrict__ ctrs,     // [N,2]
    const float* __restrict__ feats,    // [N,20,3]
    const float* __restrict__ gt,       // [N,T,2]
    const int* __restrict__ has,        // [N,T] bool -> int32
    const int* __restrict__ natgs,      // [B]
    float* __restrict__ out,
    float* __restrict__ part)           // [N,4]
{
    const int a   = blockIdx.x;
    const int tid = threadIdx.x;

    __shared__ __align__(16) float    s_stage[R_CAND * 5];
    __shared__ float4   s_goal[R_CAND];            // orig order (gx,gy,g2,g3)
    __shared__ __align__(16) float    s_logic[R_CAND];  // orig order
    __shared__ float2   s_pos[R_CAND];             // sorted by logit desc
    __shared__ int      s_sidx[R_CAND];            // sorted pos -> orig idx
    __shared__ float    s_d[R_CAND];               // dist (sorted order)
    __shared__ __align__(16) uint32_t s_col[R_CAND][4]; // suppression columns (bits i<j)
    __shared__ float    s_gtrow[T_STEPS * 2];
    __shared__ int      s_has[T_STEPS];
    __shared__ float    s_coef[NUM_MODS][6];
    __shared__ float    s_traj[NUM_MODS][T_STEPS][2];

    // ---- A1: coalesced staging + column zero-init
    {
        const float* rbase = roi + (size_t)a * R_CAND * 5;
        #pragma unroll
        for (int k = 0; k < 5; ++k) s_stage[tid + k * 128] = rbase[tid + k * 128];
    }
    *reinterpret_cast<uint4*>(&s_col[tid][0]) = make_uint4(0u, 0u, 0u, 0u);
    const float4 anc = *reinterpret_cast<const float4*>(anchor + (size_t)(a * R_CAND + tid) * 4);
    if (tid < T_STEPS * 2) s_gtrow[tid] = gt[(size_t)a * T_STEPS * 2 + tid];
    if (tid >= 64 && tid < 64 + T_STEPS) s_has[tid - 64] = has[(size_t)a * T_STEPS + (tid - 64)];
    __syncthreads();

    // ---- A2: logits + goals (stride-5 LDS read: 5 coprime 32 -> conflict-free)
    float lg, gx, gy;
    {
        const float* rp = &s_stage[tid * 5];
        lg = rp[0];
        gx = anc.x + rp[1];
        gy = anc.y + rp[2];
        s_logic[tid] = lg;
        s_goal[tid]  = make_float4(gx, gy, anc.z + rp[3], anc.w + rp[4]);
    }
    __syncthreads();

    // ---- B: rank = stable argsort(-logic) position; scatter pos/idx/dist
    {
        int rank = 0;
        for (int j = 0; j < R_CAND; j += 4) {
            const float4 v = *reinterpret_cast<const float4*>(&s_logic[j]);
            rank += (v.x > lg) || (v.x == lg && (j + 0) < tid);
            rank += (v.y > lg) || (v.y == lg && (j + 1) < tid);
            rank += (v.z > lg) || (v.z == lg && (j + 2) < tid);
            rank += (v.w > lg) || (v.w == lg && (j + 3) < tid);
        }
        s_pos[rank]  = make_float2(gx, gy);
        s_sidx[rank] = tid;
        s_d[rank]    = fabsf(gx - s_gtrow[(T_STEPS - 1) * 2]) + fabsf(gy - s_gtrow[(T_STEPS - 1) * 2 + 1]);
    }
    __syncthreads();

    // ---- C: balanced all-pairs suppression (round-robin; each lane 63-64 iters)
    //      boxes 0.5x0.5: iou>0.5 <=> wx>0 && wx*wy>1/6, wx=0.5-|dx|
    {
        const int t = tid;
        const float2 pt = s_pos[t];
        const int kmax = (t < 64) ? 64 : 63;   // pair (t,t+64) tested once (by t<64)
        for (int k = 1; k <= kmax; ++k) {
            const int p = (t + k) & (R_CAND - 1);
            const float2 pp = s_pos[p];
            const float wx = 0.5f - fabsf(pt.x - pp.x);
            const float wy = 0.5f - fabsf(pt.y - pp.y);
            if (wx > 0.0f && wx * wy > (1.0f / 6.0f)) {   // sparse: ~8 hits/agent total
                const int lo = (p < t) ? p : t;
                const int hi = (p < t) ? t : p;
                atomicOr(&s_col[hi][lo >> 5], 1u << (lo & 31));
            }
        }
    }
    __syncthreads();

    // ---- D (wave 0): ballot-fixpoint NMS -> top-6 -> coefficients
    float my_slog = 0.0f; int my_win = 0;   // valid on lanes 0..5
    if (tid < 64) {
        const uint64_t cl0 = (uint64_t)s_col[tid][0] | ((uint64_t)s_col[tid][1] << 32);       // col tid (<64): word1==0
        const uint64_t ch0 = (uint64_t)s_col[tid + 64][0] | ((uint64_t)s_col[tid + 64][1] << 32);
        const uint64_t ch1 = (uint64_t)s_col[tid + 64][2] | ((uint64_t)s_col[tid + 64][3] << 32);
        uint64_t k0 = ~0ull, k1 = ~0ull;
        for (int it = 0; it < 200; ++it) {                  // fixpoint == greedy NMS
            const int slo = ((cl0 & k0) != 0);
            const int shi = (((ch0 & k0) | (ch1 & k1)) != 0);
            const uint64_t n0 = ~__ballot(slo);
            const uint64_t n1 = ~__ballot(shi);
            if (n0 == k0 && n1 == k1) break;
            k0 = n0; k1 = n1;
        }
        const int kfall = (__popcll(k0) + __popcll(k1)) < NUM_MODS;
        float d_lo = (kfall | (int)((k0 >> tid) & 1)) ? s_d[tid]      : INFINITY;
        float d_hi = (kfall | (int)((k1 >> tid) & 1)) ? s_d[tid + 64] : INFINITY;
        int   i_lo = s_sidx[tid], i_hi = s_sidx[tid + 64];
        for (int m = 0; m < NUM_MODS; ++m) {
            float bd; int bi;
            if (d_lo < d_hi || (d_lo == d_hi && i_lo < i_hi)) { bd = d_lo; bi = i_lo; }
            else                                               { bd = d_hi; bi = i_hi; }
            for (int off = 32; off >= 1; off >>= 1) {
                const float od = __shfl_down(bd, (unsigned)off, 64);
                const int   oi = __shfl_down(bi, (unsigned)off, 64);
                if (od < bd || (od == bd && oi < bi)) { bd = od; bi = oi; }
            }
            bi = __shfl(bi, 0, 64);
            if (tid == m) my_win = bi;
            if (i_lo == bi) d_lo = INFINITY;
            if (i_hi == bi) d_hi = INFINITY;
        }
        if (tid < NUM_MODS) {
            const float ap0 = ctrs[(size_t)a * 2 + 0];
            const float ap1 = ctrs[(size_t)a * 2 + 1];
            const float ap2 = feats[((size_t)a * 20 + 19) * 3 + 0];
            const float ap3 = feats[((size_t)a * 20 + 19) * 3 + 1];
            const float4 g = s_goal[my_win];
            my_slog = s_logic[my_win];
            const float a1c = (2.f * g.x * ap2 + 2.f * ap0 * ap2) / (2.f + ap2 - g.z);
            const float a0c = g.x - ap0 - a1c;
            const float b1c = (2.f * g.y * ap3 + 2.f * ap1 * ap3) / (2.f + ap3 - g.w);
            const float b0c = g.y - ap1 - b1c;
            s_coef[tid][0] = a0c; s_coef[tid][1] = a1c; s_coef[tid][2] = ap0;
            s_coef[tid][3] = b0c; s_coef[tid][4] = b1c; s_coef[tid][5] = ap1;
        }
    }
    __syncthreads();

    // ---- E: trajectories (180 elems, strided)
    for (int p = tid; p < NUM_MODS * T_STEPS; p += 128) {
        const int m = p / T_STEPS, t = p % T_STEPS;
        const float s1 = (float)t / (float)(T_STEPS - 1);
        const float s2 = s1 * s1;
        s_traj[m][t][0] = s_coef[m][0] * s2 + s_coef[m][1] * s1 + s_coef[m][2];
        s_traj[m][t][1] = s_coef[m][3] * s2 + s_coef[m][4] * s1 + s_coef[m][5];
    }
    __syncthreads();

    // ---- F (wave 0): losses  ||  G (wave 1): traj_eval gather
    if (tid < 64) {
        float bv = -1e30f; int bt = tid;
        if (tid < T_STEPS) bv = (s_has[tid] ? 1.0f : 0.0f) + (0.1f * (float)tid) / (float)T_STEPS;
        for (int off = 16; off >= 1; off >>= 1) {
            const float ov = __shfl_down(bv, (unsigned)off, 32);
            const int   ot = __shfl_down(bt, (unsigned)off, 32);
            if (ov > bv || (ov == bv && ot < bt)) { bv = ov; bt = ot; }
        }
        const int   lt   = __shfl(bt, 0, 64);
        const float bmax = __shfl(bv, 0, 64);
        const int   mask = bmax > 1.0f;
        const float egx = s_gtrow[lt * 2 + 0], egy = s_gtrow[lt * 2 + 1];
        float md = 1e30f; int mm = tid;
        if (tid < NUM_MODS) {
            const float dx = s_traj[tid][lt][0] - egx;
            const float dy = s_traj[tid][lt][1] - egy;
            md = sqrtf(dx * dx + dy * dy);
        }
        for (int off = 4; off >= 1; off >>= 1) {
            const float ov = __shfl_down(md, (unsigned)off, 8);
            const int   om = __shfl_down(mm, (unsigned)off, 8);
            if (ov < md || (ov == md && om < mm)) { md = ov; mm = om; }
        }
        const int mi = __shfl(mm, 0, 64);
        float cv = 0.0f;
        if (tid < NUM_MODS) {
            const float l = my_slog;
            const float g = (tid == mi) ? 1.0f : 0.0f;
            cv = fmaxf(l, 0.0f) - l * g + log1pf(expf(-fabsf(l)));
        }
        cv += __shfl_xor(cv, 4, 8); cv += __shfl_xor(cv, 2, 8); cv += __shfl_xor(cv, 1, 8);
        float rv = 0.0f;
        if (tid < 2 * T_STEPS) {
            const int t = tid >> 1, c = tid & 1;
            if (mask && s_has[t]) {
                const float diff = s_traj[mi][t][c] - s_gtrow[t * 2 + c];
                const float ad = fabsf(diff);
                rv = (ad < 1.0f) ? 0.5f * diff * diff : (ad - 0.5f);
            }
        }
        for (int off = 32; off >= 1; off >>= 1) rv += __shfl_xor(rv, (unsigned)off, 64);
        const int hv = (tid < T_STEPS) ? s_has[tid] : 0;
        const int nh = __popcll(__ballot(hv != 0));
        if (tid == 0) {
            *reinterpret_cast<float4*>(&part[(size_t)a * 4]) =
                make_float4(mask ? cv : 0.0f, rv, mask ? 1.0f : 0.0f, mask ? (float)nh : 0.0f);
        }
    } else {
        // gather (temp is NOT cumsum: [0, natgs[0], ..., natgs[14]])
        const float* tp = &s_traj[0][0][0];
        const int p = tid - 64;
        for (int b = 0; b < B_BATCH; ++b) {
            const int target = (b == 0) ? 0 : natgs[b - 1];
            if (target == a) {
                for (int q = p; q < NUM_MODS * T_STEPS * 2; q += 64)
                    out[2 + (size_t)b * NUM_MODS * T_STEPS * 2 + q] = tp[q];
            }
        }
    }
}

__global__ __launch_bounds__(256) void reduce_kernel(
    const float* __restrict__ part, float* __restrict__ out)
{
    __shared__ double s0[256], s1[256], s2[256], s3[256];
    const int tid = threadIdx.x;
    double c = 0, r = 0, n = 0, w = 0;
    for (int a = tid; a < N_AGENTS; a += 256) {
        c += (double)part[(size_t)a * 4 + 0];
        r += (double)part[(size_t)a * 4 + 1];
        n += (double)part[(size_t)a * 4 + 2];
        w += (double)part[(size_t)a * 4 + 3];
    }
    s0[tid] = c; s1[tid] = r; s2[tid] = n; s3[tid] = w;
    __syncthreads();
    for (int off = 128; off >= 1; off >>= 1) {
        if (tid < off) {
            s0[tid] += s0[tid + off]; s1[tid] += s1[tid + off];
            s2[tid] += s2[tid + off]; s3[tid] += s3[tid + off];
        }
        __syncthreads();
    }
    if (tid == 0) {
        out[0]    = (float)s0[0];
        out[1]    = (float)s1[0];
        out[5762] = (float)s2[0];
        out[5763] = (float)s3[0];
    }
}

extern "C" void kernel_launch(void* const* d_in, const int* in_sizes, int n_in,
                              void* d_out, int out_size, void* d_ws, size_t ws_size,
                              hipStream_t stream) {
    const float*   roi    = (const float*)d_in[0];
    const float*   anchor = (const float*)d_in[1];
    const float*   ctrs   = (const float*)d_in[2];
    const float*   feats  = (const float*)d_in[3];
    const float*   gt     = (const float*)d_in[4];
    const int*     has    = (const int*)d_in[5];
    const int*     natgs  = (const int*)d_in[6];
    float* out  = (float*)d_out;
    float* part = (float*)d_ws;   // 2048*4 floats = 32 KB

    agent_kernel<<<N_AGENTS, 128, 0, stream>>>(roi, anchor, ctrs, feats, gt, has, natgs, out, part);
    reduce_kernel<<<1, 256, 0, stream>>>(part, out);
}